// Round 12
// baseline (265.112 us; speedup 1.0000x reference)
//
#include <hip/hip_runtime.h>
#include <stdint.h>

typedef __attribute__((ext_vector_type(8))) short bf16x8;
typedef __attribute__((ext_vector_type(4))) float f32x4;
typedef __attribute__((ext_vector_type(4))) unsigned int u32x4;

#define D_IN  4096
#define D_OUT 4096
#define KC 512   // per-component input dim
#define NC 512   // per-component output dim
#define NT 64    // K-tiles of BK=64

// SIGN_TABLE[i][j], row-major
__constant__ float c_sign[64] = {
 +1,-1,-1,-1,-1,-1,-1,-1,
 +1,+1,+1,-1,+1,-1,-1,+1,
 +1,-1,+1,+1,+1,+1,-1,-1,
 +1,+1,-1,+1,+1,-1,+1,-1,
 +1,-1,-1,-1,+1,+1,+1,+1,
 +1,+1,-1,+1,-1,+1,-1,+1,
 +1,+1,+1,-1,-1,+1,+1,-1,
 +1,-1,+1,+1,-1,-1,+1,+1,
};

__device__ inline unsigned int pack2bf16(float a, float b) {
    unsigned int ua = __builtin_bit_cast(unsigned int, a);
    unsigned int ub = __builtin_bit_cast(unsigned int, b);
    ua = (ua + 0x7FFFu + ((ua >> 16) & 1u)) >> 16;
    ub = (ub + 0x7FFFu + ((ub >> 16) & 1u)) >> 16;
    return ua | (ub << 16);
}

typedef __attribute__((address_space(1))) const unsigned int gas_u32;
typedef __attribute__((address_space(3))) unsigned int las_u32;
#define ASYNC16(g, l) __builtin_amdgcn_global_load_lds((gas_u32*)(g), (las_u32*)(l), 16, 0, 0)
#define ENDP do { __builtin_amdgcn_s_barrier(); asm volatile("" ::: "memory"); } while (0)

// ---------- fused pre-conversion kernel ----------
// blocks [0, nbx): X fp32 -> bf16 (8 elems/thread, non-temporal reads)
// blocks [nbx, nbx+nbw): Wbig[i*512+n][j*512+k] = sign[i][j]*W[i^j][n][k]
__global__ __launch_bounds__(256)
void conv_xw(const float* __restrict__ X, const float* __restrict__ W,
             unsigned short* __restrict__ Xb, unsigned short* __restrict__ Wb,
             int nbx)
{
    if ((int)blockIdx.x < nbx) {
        int i = blockIdx.x * 256 + threadIdx.x;           // 8-elem group index
        const f32x4* src = (const f32x4*)X + (size_t)i * 2;
        const f32x4 a = __builtin_nontemporal_load(src);
        const f32x4 b = __builtin_nontemporal_load(src + 1);
        u32x4 o;
        o.x = pack2bf16(a.x, a.y); o.y = pack2bf16(a.z, a.w);
        o.z = pack2bf16(b.x, b.y); o.w = pack2bf16(b.z, b.w);
        ((u32x4*)Xb)[i] = o;
    } else {
        int gid = (blockIdx.x - nbx) * 256 + threadIdx.x; // 0 .. 4096*512-1
        int row = gid >> 9;            // i*512 + n
        int c8  = gid & 511;           // col = c8*8
        int i = row >> 9, n = row & 511;
        int j = c8 >> 6;
        int k = (c8 & 63) << 3;
        float sgn = c_sign[i * 8 + j];
        const f32x4* src = (const f32x4*)(W + ((((i ^ j) * NC + n) * KC) + k));
        const f32x4 a = __builtin_nontemporal_load(src);
        const f32x4 b = __builtin_nontemporal_load(src + 1);
        u32x4 o;
        o.x = pack2bf16(a.x * sgn, a.y * sgn); o.y = pack2bf16(a.z * sgn, a.w * sgn);
        o.z = pack2bf16(b.x * sgn, b.y * sgn); o.w = pack2bf16(b.z * sgn, b.w * sgn);
        ((u32x4*)Wb)[gid] = o;
    }
}

// ---------- 256x256 bf16 GEMM, one-ahead pipeline, 1 barrier/phase (R9) ----------

__device__ __forceinline__ void read_a(bf16x8 (&d)[4], const unsigned short* buf,
                                       int mh, int kk, int lane, int wr) {
#pragma unroll
    for (int f = 0; f < 4; ++f) {
        const int r  = wr * 128 + (mh * 4 + f) * 16 + (lane & 15);
        const int ch = (kk * 4 + (lane >> 4)) ^ (r & 7);
        d[f] = *(const bf16x8*)((const char*)buf + r * 128 + (ch << 4));
    }
}

__device__ __forceinline__ void read_b(bf16x8 (&d)[4], const unsigned short* buf,
                                       int kk, int lane, int wc) {
#pragma unroll
    for (int n = 0; n < 4; ++n) {
        const int r  = wc * 64 + n * 16 + (lane & 15);
        const int ch = (kk * 4 + (lane >> 4)) ^ (r & 7);
        d[n] = *(const bf16x8*)((const char*)buf + r * 128 + (ch << 4));
    }
}

__device__ __forceinline__ void mfma16(f32x4 (&acc)[8][4], int mh,
                                       const bf16x8 (&a)[4], const bf16x8 (&b)[4]) {
#pragma unroll
    for (int f = 0; f < 4; ++f)
#pragma unroll
        for (int n = 0; n < 4; ++n)
            acc[mh * 4 + f][n] = __builtin_amdgcn_mfma_f32_16x16x32_bf16(
                a[f], b[n], acc[mh * 4 + f][n], 0, 0, 0);
}

// One K-tile (BK=64), 4 phases, ONE barrier per phase (at phase end) — the
// round-9-verified schedule (best measured: 219 µs dispatch, 0 conflicts).
// Race audit: see round-9 notes; unchanged byte-for-byte.
__device__ __forceinline__ void ktile_pipe(
    const unsigned short* Ac, const unsigned short* Bc,
    const unsigned short* An, const unsigned short* Bn,
    unsigned short* stA, unsigned short* stB,
    const unsigned short* gA1, const unsigned short* gB2,
    f32x4 (&acc)[8][4],
    bf16x8 (&aX)[4], bf16x8 (&aY)[4], bf16x8 (&bX)[4], bf16x8 (&bY)[4],
    size_t goff0, size_t goff1, int loff0, int loff1,
    int lane, int wr, int wc)
{
    // ---- P0: compute (mh0,kh0) = aX*bX; prefetch aY=(mh1,kh0) ----
    read_a(aY, Ac, 1, 0, lane, wr);
    ASYNC16(gA1 + goff0, stA + loff0);
    ASYNC16(gA1 + goff1, stA + loff1);
    __builtin_amdgcn_s_setprio(1);
    mfma16(acc, 0, aX, bX);
    __builtin_amdgcn_s_setprio(0);
    ENDP;
    // ---- P1: compute (mh1,kh0) = aY*bX; prefetch aX=(mh0,kh1), bY=(kh1) ----
    read_a(aX, Ac, 0, 1, lane, wr);
    read_b(bY, Bc, 1, lane, wc);
    ASYNC16(gA1 + 128 * D_IN + goff0, stA + 8192 + loff0);
    ASYNC16(gA1 + 128 * D_IN + goff1, stA + 8192 + loff1);
    __builtin_amdgcn_s_setprio(1);
    mfma16(acc, 1, aY, bX);
    __builtin_amdgcn_s_setprio(0);
    ENDP;
    // ---- P2: compute (mh0,kh1) = aX*bY; prefetch aY=(mh1,kh1) ----
    read_a(aY, Ac, 1, 1, lane, wr);
    ASYNC16(gB2 + goff0, stB + loff0);
    ASYNC16(gB2 + goff1, stB + loff1);
    __builtin_amdgcn_s_setprio(1);
    mfma16(acc, 0, aX, bY);
    __builtin_amdgcn_s_setprio(0);
    asm volatile("s_waitcnt vmcnt(2)");   // A(u+1)+B(u+1) landed -> P3 may read An/Bn
    ENDP;
    // ---- P3: compute (mh1,kh1) = aY*bY; prefetch NEXT tile aX, bX ----
    read_a(aX, An, 0, 0, lane, wr);
    read_b(bX, Bn, 0, lane, wc);
    ASYNC16(gB2 + 128 * D_IN + goff0, stB + 8192 + loff0);
    ASYNC16(gB2 + 128 * D_IN + goff1, stB + 8192 + loff1);
    __builtin_amdgcn_s_setprio(1);
    mfma16(acc, 1, aY, bY);
    __builtin_amdgcn_s_setprio(0);
    ENDP;
}

__global__ __launch_bounds__(512, 2)
void octo_gemm_8ph(const unsigned short* __restrict__ Xb,
                   const unsigned short* __restrict__ Wb,
                   float* __restrict__ Y, int M)
{
    // LDS: 2 K-tile double buffer; A(256x64) + B(256x64) bf16 each = 128 KiB.
    // Element (r,k): byte r*128 + ((chunk ^ (r&7))<<4) + low, chunk=(k*2)>>4;
    // linear LDS dest + inverse-swizzled GLOBAL source (rule #21).
    __shared__ __align__(16) unsigned short sm[65536];
    unsigned short* A0 = sm;
    unsigned short* A1 = sm + 16384;
    unsigned short* B0 = sm + 32768;
    unsigned short* B1 = sm + 49152;

    const int tid  = threadIdx.x;
    const int lane = tid & 63;
    const int wave = tid >> 6;
    const int wr   = wave >> 2;      // 2x4 wave grid; wave owns 128x64 output
    const int wc   = wave & 3;

    const int nbn = D_OUT / 256;                // 16
    const int nwg = (M / 256) * nbn;            // 512
    int bid = blockIdx.x;
    int cpx = nwg >> 3;                         // bijective XCD swizzle (nwg%8==0)
    int wg  = (bid & 7) * cpx + (bid >> 3);
    const int bm = wg / nbn, bn = wg % nbn;
    const int row0 = bm * 256, col0 = bn * 256;

    // staging geometry: half-tile = 128 rows x 64 cols bf16; 2 loads/thread
    const int srow  = tid >> 3;                 // 0..63
    const int sch   = tid & 7;                  // 16B chunk
    const size_t goff0 = (size_t)srow * D_IN + (size_t)((sch ^ (srow & 7)) * 8);
    const size_t goff1 = goff0 + (size_t)64 * D_IN;   // (64+srow)&7 == srow&7
    const int loff0 = tid * 8;                  // ushort elems; = lane*16B per wave
    const int loff1 = loff0 + 4096;

    const unsigned short* gX = Xb + (size_t)row0 * D_IN;
    const unsigned short* gW = Wb + (size_t)col0 * D_IN;

    f32x4 acc[8][4];
    #pragma unroll
    for (int m = 0; m < 8; ++m)
        #pragma unroll
        for (int n = 0; n < 4; ++n)
            acc[m][n] = (f32x4){0.f, 0.f, 0.f, 0.f};

    // ---- prologue: tile0 A+B -> buf0, tile1 B -> buf1.B (6 half-tiles) ----
    ASYNC16(gX + goff0, A0 + loff0);              ASYNC16(gX + goff1, A0 + loff1);
    ASYNC16(gX + 128 * D_IN + goff0, A0 + 8192 + loff0);
    ASYNC16(gX + 128 * D_IN + goff1, A0 + 8192 + loff1);
    ASYNC16(gW + goff0, B0 + loff0);              ASYNC16(gW + goff1, B0 + loff1);
    ASYNC16(gW + 128 * D_IN + goff0, B0 + 8192 + loff0);
    ASYNC16(gW + 128 * D_IN + goff1, B0 + 8192 + loff1);
    ASYNC16(gW + 64 + goff0, B1 + loff0);         ASYNC16(gW + 64 + goff1, B1 + loff1);
    ASYNC16(gW + 64 + 128 * D_IN + goff0, B1 + 8192 + loff0);
    ASYNC16(gW + 64 + 128 * D_IN + goff1, B1 + 8192 + loff1);
    asm volatile("s_waitcnt vmcnt(4)");           // tile0's 8 loads landed
    ENDP;

    // prime the register pipeline: tile0's (mh0,kh0) A-frags + b(kh0)
    bf16x8 aX[4], aY[4], bX[4], bY[4];
    read_a(aX, A0, 0, 0, lane, wr);
    read_b(bX, B0, 0, lane, wc);

    for (int i = 0; i < NT / 2; ++i) {
        const int u = 2 * i;
        // tail iterations stage wrapped tiles (&63): keeps vmcnt counts uniform;
        // wrapped data lands in regions never read again (race-free; last
        // tile's P3 cross-tile prefetch reads dead values that feed no MFMA).
        const unsigned short* gA1t = gX + ((u + 1) & (NT - 1)) * 64;
        const unsigned short* gA2t = gX + ((u + 2) & (NT - 1)) * 64;
        const unsigned short* gB2t = gW + ((u + 2) & (NT - 1)) * 64;
        const unsigned short* gB3t = gW + ((u + 3) & (NT - 1)) * 64;

        // tile u from buf0: stage A(u+1)->A1, B(u+2)->B0; P3 prefetch from A1/B1
        ktile_pipe(A0, B0, A1, B1, A1, B0, gA1t, gB2t,
                   acc, aX, aY, bX, bY,
                   goff0, goff1, loff0, loff1, lane, wr, wc);
        // tile u+1 from buf1: stage A(u+2)->A0, B(u+3)->B1; P3 prefetch from A0/B0
        ktile_pipe(A1, B1, A0, B0, A0, B1, gA2t, gB3t,
                   acc, aX, aY, bX, bY,
                   goff0, goff1, loff0, loff1, lane, wr, wc);
    }

    // epilogue: C/D layout col=lane&15, row=(lane>>4)*4+reg  [m89/m91]
    // Non-temporal stores: Y is write-once-never-read — keep it out of L2/L3
    // so the Xb/Wb working set stays resident (FETCH was 3.2x ideal).
    const int rl = (lane >> 4) << 2;
    const int cl = lane & 15;
    #pragma unroll
    for (int m = 0; m < 8; ++m) {
        const int rg = row0 + wr * 128 + m * 16 + rl;
        #pragma unroll
        for (int n = 0; n < 4; ++n) {
            const int cg = col0 + wc * 64 + n * 16 + cl;
            #pragma unroll
            for (int q = 0; q < 4; ++q)
                __builtin_nontemporal_store(acc[m][n][q],
                                            &Y[(size_t)(rg + q) * D_OUT + cg]);
        }
    }
}

// ---------- fallback: fused fp32-staging kernel (no workspace) ----------

#define BM 128
#define BN 128
#define BK 64

__global__ __launch_bounds__(256)
void octo_gemm_f32(const float* __restrict__ X, const float* __restrict__ W,
                   float* __restrict__ Y, int M)
{
    __shared__ __align__(16) unsigned short As[BM * BK];
    __shared__ __align__(16) unsigned short Bs[BN * BK];

    const int tid  = threadIdx.x;
    const int lane = tid & 63;
    const int wave = tid >> 6;
    const int wr   = wave >> 1;
    const int wc   = wave & 1;

    const int nbn = D_OUT / BN;
    const int nwg = (M / BM) * nbn;
    int bid = blockIdx.x;
    int wg  = bid;
    if ((nwg & 7) == 0) {
        int cpx = nwg >> 3;
        wg = (bid & 7) * cpx + (bid >> 3);
    }
    const int bm = wg / nbn, bn = wg % nbn;
    const int row0  = bm * BM;
    const int col0  = bn * BN;
    const int icomp = col0 >> 9;
    const int noff  = col0 & (NC - 1);

    const int srow = tid >> 4;
    const int scol = (tid & 15) << 2;

    f32x4 acc[4][4];
    #pragma unroll
    for (int m = 0; m < 4; ++m)
        #pragma unroll
        for (int n = 0; n < 4; ++n)
            acc[m][n] = (f32x4){0.f, 0.f, 0.f, 0.f};

    char* AsB = (char*)As;
    char* BsB = (char*)Bs;
    const int byteC = scol << 1;

    for (int step = 0; step < NT; ++step) {
        const int k0 = step * BK;
        const int j  = k0 >> 9;
        const int kc = k0 & (KC - 1);
        const float sgn = c_sign[icomp * 8 + j];
        const int   w   = icomp ^ j;
        const float* Wp = W + (((size_t)w * NC + noff) * KC + kc);
        const float* Xp = X + ((size_t)row0 * D_IN + k0);

        __syncthreads();
        #pragma unroll
        for (int p = 0; p < 8; ++p) {
            const int r  = p * 16 + srow;
            const int sb = r * 128 + ((((byteC >> 4) ^ (r & 7)) << 4)) + (byteC & 8);
            const float4 va = *(const float4*)(&Xp[(size_t)r * D_IN + scol]);
            *(uint2*)(AsB + sb) = make_uint2(pack2bf16(va.x, va.y),
                                             pack2bf16(va.z, va.w));
            const float4 vb = *(const float4*)(&Wp[(size_t)r * KC + scol]);
            *(uint2*)(BsB + sb) = make_uint2(pack2bf16(vb.x * sgn, vb.y * sgn),
                                             pack2bf16(vb.z * sgn, vb.w * sgn));
        }
        __syncthreads();

        #pragma unroll
        for (int kk = 0; kk < 2; ++kk) {
            bf16x8 af[4], bf[4];
            #pragma unroll
            for (int m = 0; m < 4; ++m) {
                const int r = wr * 64 + m * 16 + (lane & 15);
                const int chunk = (kk * 4 + (lane >> 4)) ^ (r & 7);
                af[m] = *(const bf16x8*)(AsB + r * 128 + (chunk << 4));
            }
            #pragma unroll
            for (int n = 0; n < 4; ++n) {
                const int r = wc * 64 + n * 16 + (lane & 15);
                const int chunk = (kk * 4 + (lane >> 4)) ^ (r & 7);
                bf[n] = *(const bf16x8*)(BsB + r * 128 + (chunk << 4));
            }
            #pragma unroll
            for (int m = 0; m < 4; ++m)
                #pragma unroll
                for (int n = 0; n < 4; ++n)
                    acc[m][n] = __builtin_amdgcn_mfma_f32_16x16x32_bf16(
                        af[m], bf[n], acc[m][n], 0, 0, 0);
        }
    }

    const int rl = (lane >> 4) << 2;
    const int cl = lane & 15;
    #pragma unroll
    for (int m = 0; m < 4; ++m) {
        const int rg = row0 + wr * 64 + m * 16 + rl;
        #pragma unroll
        for (int n = 0; n < 4; ++n) {
            const int cg = col0 + wc * 64 + n * 16 + cl;
            #pragma unroll
            for (int q = 0; q < 4; ++q)
                Y[(size_t)(rg + q) * D_OUT + cg] = acc[m][n][q];
        }
    }
}

extern "C" void kernel_launch(void* const* d_in, const int* in_sizes, int n_in,
                              void* d_out, int out_size, void* d_ws, size_t ws_size,
                              hipStream_t stream) {
    const float* X = (const float*)d_in[0];   // [B*T, 4096] fp32
    const float* W = (const float*)d_in[1];   // [8, 512, 512] fp32
    float* Y = (float*)d_out;                 // [B*T, 4096] fp32
    const int M = in_sizes[0] / D_IN;         // 8192

    const size_t xb_bytes = (size_t)M * D_IN * sizeof(unsigned short);      // 64 MB
    const size_t wb_bytes = (size_t)D_OUT * D_IN * sizeof(unsigned short);  // 32 MB

    if (ws_size >= xb_bytes + wb_bytes && (M % 256) == 0) {
        unsigned short* Xb = (unsigned short*)d_ws;
        unsigned short* Wb = (unsigned short*)((char*)d_ws + xb_bytes);
        const int nbx = (M * D_IN / 8) / 256;            // conv_x blocks
        const int nbw = ((D_OUT * D_IN / 8)) / 256;      // conv_w blocks
        hipLaunchKernelGGL(conv_xw, dim3(nbx + nbw), dim3(256), 0, stream,
                           X, W, Xb, Wb, nbx);
        const int nwg = (M / 256) * (D_OUT / 256);       // 512
        hipLaunchKernelGGL(octo_gemm_8ph, dim3(nwg), dim3(512), 0, stream, Xb, Wb, Y, M);
    } else {
        const int nwg = (M / BM) * (D_OUT / BN);
        hipLaunchKernelGGL(octo_gemm_f32, dim3(nwg), dim3(256), 0, stream, X, W, Y, M);
    }
}

// Round 13
// 255.965 us; speedup vs baseline: 1.0357x; 1.0357x over previous
//
#include <hip/hip_runtime.h>
#include <stdint.h>

typedef __attribute__((ext_vector_type(8))) short bf16x8;
typedef __attribute__((ext_vector_type(4))) float f32x4;

#define D_IN  4096
#define D_OUT 4096
#define KC 512   // per-component input dim
#define NC 512   // per-component output dim
#define NT 64    // K-tiles of BK=64

// SIGN_TABLE[i][j], row-major
__constant__ float c_sign[64] = {
 +1,-1,-1,-1,-1,-1,-1,-1,
 +1,+1,+1,-1,+1,-1,-1,+1,
 +1,-1,+1,+1,+1,+1,-1,-1,
 +1,+1,-1,+1,+1,-1,+1,-1,
 +1,-1,-1,-1,+1,+1,+1,+1,
 +1,+1,-1,+1,-1,+1,-1,+1,
 +1,+1,+1,-1,-1,+1,+1,-1,
 +1,-1,+1,+1,-1,-1,+1,+1,
};

__device__ inline unsigned int pack2bf16(float a, float b) {
    unsigned int ua = __builtin_bit_cast(unsigned int, a);
    unsigned int ub = __builtin_bit_cast(unsigned int, b);
    ua = (ua + 0x7FFFu + ((ua >> 16) & 1u)) >> 16;
    ub = (ub + 0x7FFFu + ((ub >> 16) & 1u)) >> 16;
    return ua | (ub << 16);
}

typedef __attribute__((address_space(1))) const unsigned int gas_u32;
typedef __attribute__((address_space(3))) unsigned int las_u32;
#define ASYNC16(g, l) __builtin_amdgcn_global_load_lds((gas_u32*)(g), (las_u32*)(l), 16, 0, 0)
#define ENDP do { __builtin_amdgcn_s_barrier(); asm volatile("" ::: "memory"); } while (0)

// ---------- fused pre-conversion kernel (single launch) ----------
// blocks [0, nbx): X fp32 -> bf16 (8 elems/thread)
// blocks [nbx, nbx+nbw): Wbig[i*512+n][j*512+k] = sign[i][j]*W[i^j][n][k]
__global__ __launch_bounds__(256)
void conv_xw(const float* __restrict__ X, const float* __restrict__ W,
             unsigned short* __restrict__ Xb, unsigned short* __restrict__ Wb,
             int nbx)
{
    if ((int)blockIdx.x < nbx) {
        int i = blockIdx.x * 256 + threadIdx.x;           // 8-elem group index
        const float4 a = ((const float4*)X)[(size_t)i * 2];
        const float4 b = ((const float4*)X)[(size_t)i * 2 + 1];
        uint4 o;
        o.x = pack2bf16(a.x, a.y); o.y = pack2bf16(a.z, a.w);
        o.z = pack2bf16(b.x, b.y); o.w = pack2bf16(b.z, b.w);
        ((uint4*)Xb)[i] = o;
    } else {
        int gid = (blockIdx.x - nbx) * 256 + threadIdx.x; // 0 .. 4096*512-1
        int row = gid >> 9;            // i*512 + n
        int c8  = gid & 511;           // col = c8*8
        int i = row >> 9, n = row & 511;
        int j = c8 >> 6;
        int k = (c8 & 63) << 3;
        float sgn = c_sign[i * 8 + j];
        const float* src = W + ((((i ^ j) * NC + n) * KC) + k);
        float4 a = *(const float4*)(src);
        float4 b = *(const float4*)(src + 4);
        uint4 o;
        o.x = pack2bf16(a.x * sgn, a.y * sgn); o.y = pack2bf16(a.z * sgn, a.w * sgn);
        o.z = pack2bf16(b.x * sgn, b.y * sgn); o.w = pack2bf16(b.z * sgn, b.w * sgn);
        ((uint4*)Wb)[gid] = o;
    }
}

// ---------- 256x256 bf16 GEMM, one-ahead pipeline, 1 barrier/phase (R9) ----------

__device__ __forceinline__ void read_a(bf16x8 (&d)[4], const unsigned short* buf,
                                       int mh, int kk, int lane, int wr) {
#pragma unroll
    for (int f = 0; f < 4; ++f) {
        const int r  = wr * 128 + (mh * 4 + f) * 16 + (lane & 15);
        const int ch = (kk * 4 + (lane >> 4)) ^ (r & 7);
        d[f] = *(const bf16x8*)((const char*)buf + r * 128 + (ch << 4));
    }
}

__device__ __forceinline__ void read_b(bf16x8 (&d)[4], const unsigned short* buf,
                                       int kk, int lane, int wc) {
#pragma unroll
    for (int n = 0; n < 4; ++n) {
        const int r  = wc * 64 + n * 16 + (lane & 15);
        const int ch = (kk * 4 + (lane >> 4)) ^ (r & 7);
        d[n] = *(const bf16x8*)((const char*)buf + r * 128 + (ch << 4));
    }
}

__device__ __forceinline__ void mfma16(f32x4 (&acc)[8][4], int mh,
                                       const bf16x8 (&a)[4], const bf16x8 (&b)[4]) {
#pragma unroll
    for (int f = 0; f < 4; ++f)
#pragma unroll
        for (int n = 0; n < 4; ++n)
            acc[mh * 4 + f][n] = __builtin_amdgcn_mfma_f32_16x16x32_bf16(
                a[f], b[n], acc[mh * 4 + f][n], 0, 0, 0);
}

// One K-tile (BK=64), 4 phases, ONE barrier per phase (at phase end) — the
// round-9-verified schedule (best measured: 219 µs dispatch, 0 conflicts,
// MfmaUtil 57.8%). Race audit: see round-9 notes; unchanged byte-for-byte.
__device__ __forceinline__ void ktile_pipe(
    const unsigned short* Ac, const unsigned short* Bc,
    const unsigned short* An, const unsigned short* Bn,
    unsigned short* stA, unsigned short* stB,
    const unsigned short* gA1, const unsigned short* gB2,
    f32x4 (&acc)[8][4],
    bf16x8 (&aX)[4], bf16x8 (&aY)[4], bf16x8 (&bX)[4], bf16x8 (&bY)[4],
    size_t goff0, size_t goff1, int loff0, int loff1,
    int lane, int wr, int wc)
{
    // ---- P0: compute (mh0,kh0) = aX*bX; prefetch aY=(mh1,kh0) ----
    read_a(aY, Ac, 1, 0, lane, wr);
    ASYNC16(gA1 + goff0, stA + loff0);
    ASYNC16(gA1 + goff1, stA + loff1);
    __builtin_amdgcn_s_setprio(1);
    mfma16(acc, 0, aX, bX);
    __builtin_amdgcn_s_setprio(0);
    ENDP;
    // ---- P1: compute (mh1,kh0) = aY*bX; prefetch aX=(mh0,kh1), bY=(kh1) ----
    read_a(aX, Ac, 0, 1, lane, wr);
    read_b(bY, Bc, 1, lane, wc);
    ASYNC16(gA1 + 128 * D_IN + goff0, stA + 8192 + loff0);
    ASYNC16(gA1 + 128 * D_IN + goff1, stA + 8192 + loff1);
    __builtin_amdgcn_s_setprio(1);
    mfma16(acc, 1, aY, bX);
    __builtin_amdgcn_s_setprio(0);
    ENDP;
    // ---- P2: compute (mh0,kh1) = aX*bY; prefetch aY=(mh1,kh1) ----
    read_a(aY, Ac, 1, 1, lane, wr);
    ASYNC16(gB2 + goff0, stB + loff0);
    ASYNC16(gB2 + goff1, stB + loff1);
    __builtin_amdgcn_s_setprio(1);
    mfma16(acc, 0, aX, bY);
    __builtin_amdgcn_s_setprio(0);
    asm volatile("s_waitcnt vmcnt(2)");   // A(u+1)+B(u+1) landed -> P3 may read An/Bn
    ENDP;
    // ---- P3: compute (mh1,kh1) = aY*bY; prefetch NEXT tile aX, bX ----
    read_a(aX, An, 0, 0, lane, wr);
    read_b(bX, Bn, 0, lane, wc);
    ASYNC16(gB2 + 128 * D_IN + goff0, stB + 8192 + loff0);
    ASYNC16(gB2 + 128 * D_IN + goff1, stB + 8192 + loff1);
    __builtin_amdgcn_s_setprio(1);
    mfma16(acc, 1, aY, bY);
    __builtin_amdgcn_s_setprio(0);
    ENDP;
}

__global__ __launch_bounds__(512, 2)
void octo_gemm_8ph(const unsigned short* __restrict__ Xb,
                   const unsigned short* __restrict__ Wb,
                   float* __restrict__ Y, int M)
{
    // LDS: 2 K-tile double buffer; A(256x64) + B(256x64) bf16 each = 128 KiB.
    // Element (r,k): byte r*128 + ((chunk ^ (r&7))<<4) + low, chunk=(k*2)>>4;
    // linear LDS dest + inverse-swizzled GLOBAL source (rule #21).
    __shared__ __align__(16) unsigned short sm[65536];
    unsigned short* A0 = sm;
    unsigned short* A1 = sm + 16384;
    unsigned short* B0 = sm + 32768;
    unsigned short* B1 = sm + 49152;

    const int tid  = threadIdx.x;
    const int lane = tid & 63;
    const int wave = tid >> 6;
    const int wr   = wave >> 2;      // 2x4 wave grid; wave owns 128x64 output
    const int wc   = wave & 3;

    const int nbn = D_OUT / 256;                // 16
    const int nwg = (M / 256) * nbn;            // 512
    int bid = blockIdx.x;
    int cpx = nwg >> 3;                         // bijective XCD swizzle (nwg%8==0)
    int wg  = (bid & 7) * cpx + (bid >> 3);
    const int bm = wg / nbn, bn = wg % nbn;
    const int row0 = bm * 256, col0 = bn * 256;

    // staging geometry: half-tile = 128 rows x 64 cols bf16; 2 loads/thread
    const int srow  = tid >> 3;                 // 0..63
    const int sch   = tid & 7;                  // 16B chunk
    const size_t goff0 = (size_t)srow * D_IN + (size_t)((sch ^ (srow & 7)) * 8);
    const size_t goff1 = goff0 + (size_t)64 * D_IN;   // (64+srow)&7 == srow&7
    const int loff0 = tid * 8;                  // ushort elems; = lane*16B per wave
    const int loff1 = loff0 + 4096;

    const unsigned short* gX = Xb + (size_t)row0 * D_IN;
    const unsigned short* gW = Wb + (size_t)col0 * D_IN;

    f32x4 acc[8][4];
    #pragma unroll
    for (int m = 0; m < 8; ++m)
        #pragma unroll
        for (int n = 0; n < 4; ++n)
            acc[m][n] = (f32x4){0.f, 0.f, 0.f, 0.f};

    // ---- prologue: tile0 A+B -> buf0, tile1 B -> buf1.B (6 half-tiles) ----
    ASYNC16(gX + goff0, A0 + loff0);              ASYNC16(gX + goff1, A0 + loff1);
    ASYNC16(gX + 128 * D_IN + goff0, A0 + 8192 + loff0);
    ASYNC16(gX + 128 * D_IN + goff1, A0 + 8192 + loff1);
    ASYNC16(gW + goff0, B0 + loff0);              ASYNC16(gW + goff1, B0 + loff1);
    ASYNC16(gW + 128 * D_IN + goff0, B0 + 8192 + loff0);
    ASYNC16(gW + 128 * D_IN + goff1, B0 + 8192 + loff1);
    ASYNC16(gW + 64 + goff0, B1 + loff0);         ASYNC16(gW + 64 + goff1, B1 + loff1);
    ASYNC16(gW + 64 + 128 * D_IN + goff0, B1 + 8192 + loff0);
    ASYNC16(gW + 64 + 128 * D_IN + goff1, B1 + 8192 + loff1);
    asm volatile("s_waitcnt vmcnt(4)");           // tile0's 8 loads landed
    ENDP;

    // prime the register pipeline: tile0's (mh0,kh0) A-frags + b(kh0)
    bf16x8 aX[4], aY[4], bX[4], bY[4];
    read_a(aX, A0, 0, 0, lane, wr);
    read_b(bX, B0, 0, lane, wc);

    for (int i = 0; i < NT / 2; ++i) {
        const int u = 2 * i;
        // tail iterations stage wrapped tiles (&63): keeps vmcnt counts uniform;
        // wrapped data lands in regions never read again (race-free; last
        // tile's P3 cross-tile prefetch reads dead values that feed no MFMA).
        const unsigned short* gA1t = gX + ((u + 1) & (NT - 1)) * 64;
        const unsigned short* gA2t = gX + ((u + 2) & (NT - 1)) * 64;
        const unsigned short* gB2t = gW + ((u + 2) & (NT - 1)) * 64;
        const unsigned short* gB3t = gW + ((u + 3) & (NT - 1)) * 64;

        // tile u from buf0: stage A(u+1)->A1, B(u+2)->B0; P3 prefetch from A1/B1
        ktile_pipe(A0, B0, A1, B1, A1, B0, gA1t, gB2t,
                   acc, aX, aY, bX, bY,
                   goff0, goff1, loff0, loff1, lane, wr, wc);
        // tile u+1 from buf1: stage A(u+2)->A0, B(u+3)->B1; P3 prefetch from A0/B0
        ktile_pipe(A1, B1, A0, B0, A0, B1, gA2t, gB3t,
                   acc, aX, aY, bX, bY,
                   goff0, goff1, loff0, loff1, lane, wr, wc);
    }

    // epilogue: C/D layout col=lane&15, row=(lane>>4)*4+reg  [m89/m91]
    const int rl = (lane >> 4) << 2;
    const int cl = lane & 15;
    #pragma unroll
    for (int m = 0; m < 8; ++m) {
        const int rg = row0 + wr * 128 + m * 16 + rl;
        #pragma unroll
        for (int n = 0; n < 4; ++n) {
            const int cg = col0 + wc * 64 + n * 16 + cl;
            #pragma unroll
            for (int q = 0; q < 4; ++q)
                Y[(size_t)(rg + q) * D_OUT + cg] = acc[m][n][q];
        }
    }
}

// ---------- fallback: fused fp32-staging kernel (no workspace) ----------

#define BM 128
#define BN 128
#define BK 64

__global__ __launch_bounds__(256)
void octo_gemm_f32(const float* __restrict__ X, const float* __restrict__ W,
                   float* __restrict__ Y, int M)
{
    __shared__ __align__(16) unsigned short As[BM * BK];
    __shared__ __align__(16) unsigned short Bs[BN * BK];

    const int tid  = threadIdx.x;
    const int lane = tid & 63;
    const int wave = tid >> 6;
    const int wr   = wave >> 1;
    const int wc   = wave & 1;

    const int nbn = D_OUT / BN;
    const int nwg = (M / BM) * nbn;
    int bid = blockIdx.x;
    int wg  = bid;
    if ((nwg & 7) == 0) {
        int cpx = nwg >> 3;
        wg = (bid & 7) * cpx + (bid >> 3);
    }
    const int bm = wg / nbn, bn = wg % nbn;
    const int row0  = bm * BM;
    const int col0  = bn * BN;
    const int icomp = col0 >> 9;
    const int noff  = col0 & (NC - 1);

    const int srow = tid >> 4;
    const int scol = (tid & 15) << 2;

    f32x4 acc[4][4];
    #pragma unroll
    for (int m = 0; m < 4; ++m)
        #pragma unroll
        for (int n = 0; n < 4; ++n)
            acc[m][n] = (f32x4){0.f, 0.f, 0.f, 0.f};

    char* AsB = (char*)As;
    char* BsB = (char*)Bs;
    const int byteC = scol << 1;

    for (int step = 0; step < NT; ++step) {
        const int k0 = step * BK;
        const int j  = k0 >> 9;
        const int kc = k0 & (KC - 1);
        const float sgn = c_sign[icomp * 8 + j];
        const int   w   = icomp ^ j;
        const float* Wp = W + (((size_t)w * NC + noff) * KC + kc);
        const float* Xp = X + ((size_t)row0 * D_IN + k0);

        __syncthreads();
        #pragma unroll
        for (int p = 0; p < 8; ++p) {
            const int r  = p * 16 + srow;
            const int sb = r * 128 + ((((byteC >> 4) ^ (r & 7)) << 4)) + (byteC & 8);
            const float4 va = *(const float4*)(&Xp[(size_t)r * D_IN + scol]);
            *(uint2*)(AsB + sb) = make_uint2(pack2bf16(va.x, va.y),
                                             pack2bf16(va.z, va.w));
            const float4 vb = *(const float4*)(&Wp[(size_t)r * KC + scol]);
            *(uint2*)(BsB + sb) = make_uint2(pack2bf16(vb.x * sgn, vb.y * sgn),
                                             pack2bf16(vb.z * sgn, vb.w * sgn));
        }
        __syncthreads();

        #pragma unroll
        for (int kk = 0; kk < 2; ++kk) {
            bf16x8 af[4], bf[4];
            #pragma unroll
            for (int m = 0; m < 4; ++m) {
                const int r = wr * 64 + m * 16 + (lane & 15);
                const int chunk = (kk * 4 + (lane >> 4)) ^ (r & 7);
                af[m] = *(const bf16x8*)(AsB + r * 128 + (chunk << 4));
            }
            #pragma unroll
            for (int n = 0; n < 4; ++n) {
                const int r = wc * 64 + n * 16 + (lane & 15);
                const int chunk = (kk * 4 + (lane >> 4)) ^ (r & 7);
                bf[n] = *(const bf16x8*)(BsB + r * 128 + (chunk << 4));
            }
            #pragma unroll
            for (int m = 0; m < 4; ++m)
                #pragma unroll
                for (int n = 0; n < 4; ++n)
                    acc[m][n] = __builtin_amdgcn_mfma_f32_16x16x32_bf16(
                        af[m], bf[n], acc[m][n], 0, 0, 0);
        }
    }

    const int rl = (lane >> 4) << 2;
    const int cl = lane & 15;
    #pragma unroll
    for (int m = 0; m < 4; ++m) {
        const int rg = row0 + wr * 64 + m * 16 + rl;
        #pragma unroll
        for (int n = 0; n < 4; ++n) {
            const int cg = col0 + wc * 64 + n * 16 + cl;
            #pragma unroll
            for (int q = 0; q < 4; ++q)
                Y[(size_t)(rg + q) * D_OUT + cg] = acc[m][n][q];
        }
    }
}

extern "C" void kernel_launch(void* const* d_in, const int* in_sizes, int n_in,
                              void* d_out, int out_size, void* d_ws, size_t ws_size,
                              hipStream_t stream) {
    const float* X = (const float*)d_in[0];   // [B*T, 4096] fp32
    const float* W = (const float*)d_in[1];   // [8, 512, 512] fp32
    float* Y = (float*)d_out;                 // [B*T, 4096] fp32
    const int M = in_sizes[0] / D_IN;         // 8192

    const size_t xb_bytes = (size_t)M * D_IN * sizeof(unsigned short);      // 64 MB
    const size_t wb_bytes = (size_t)D_OUT * D_IN * sizeof(unsigned short);  // 32 MB

    if (ws_size >= xb_bytes + wb_bytes && (M % 256) == 0) {
        unsigned short* Xb = (unsigned short*)d_ws;
        unsigned short* Wb = (unsigned short*)((char*)d_ws + xb_bytes);
        const int nbx = (M * D_IN / 8) / 256;            // conv_x blocks
        const int nbw = ((D_OUT * D_IN / 8)) / 256;      // conv_w blocks
        hipLaunchKernelGGL(conv_xw, dim3(nbx + nbw), dim3(256), 0, stream,
                           X, W, Xb, Wb, nbx);
        const int nwg = (M / 256) * (D_OUT / 256);       // 512
        hipLaunchKernelGGL(octo_gemm_8ph, dim3(nwg), dim3(512), 0, stream, Xb, Wb, Y, M);
    } else {
        const int nwg = (M / BM) * (D_OUT / BN);
        hipLaunchKernelGGL(octo_gemm_f32, dim3(nwg), dim3(256), 0, stream, X, W, Y, M);
    }
}